// Round 1
// baseline (8872.402 us; speedup 1.0000x reference)
//
#include <hip/hip_runtime.h>
#include <math.h>

#define NN 512
#define DD 8192

// ---------------- row-norm scales: scale[m][r] = 1 / max(||row||, 1e-6) ----------------
__global__ __launch_bounds__(256) void norm_kernel(
    const float* __restrict__ a0, const float* __restrict__ a1,
    const float* __restrict__ a2, float* __restrict__ scales) {
  const float* mats[3] = {a0, a1, a2};
  const int m = blockIdx.y;
  const int row = blockIdx.x;
  const float* x = mats[m] + (size_t)row * DD;
  const int tid = threadIdx.x;
  float s = 0.f;
  for (int k = tid * 4; k < DD; k += 256 * 4) {
    const float4 v = *(const float4*)(x + k);
    s += v.x * v.x + v.y * v.y + v.z * v.z + v.w * v.w;
  }
#pragma unroll
  for (int off = 32; off > 0; off >>= 1) s += __shfl_down(s, off);
  __shared__ float ws[4];
  if ((tid & 63) == 0) ws[tid >> 6] = s;
  __syncthreads();
  if (tid == 0) {
    const float t = ws[0] + ws[1] + ws[2] + ws[3];
    scales[m * NN + row] = 1.0f / fmaxf(sqrtf(t), 1e-6f);
  }
}

// ---------------- cost_p = 1 - (A B^T) * sa * sb, p: (0:1->2, 1:2->3, 2:3->1) ----------
__global__ __launch_bounds__(256) void cost_gemm_kernel(
    const float* __restrict__ a0, const float* __restrict__ a1,
    const float* __restrict__ a2, const float* __restrict__ scales,
    float* __restrict__ cost_all) {
  const float* mats[3] = {a0, a1, a2};
  const int p = blockIdx.z;
  const int pA = p, pB = (p + 1) % 3;
  const float* A = mats[pA];
  const float* B = mats[pB];
  float* C = cost_all + (size_t)p * NN * NN;

  __shared__ float lds_a[32 * 64];
  __shared__ float lds_b[32 * 64];

  const int tid = threadIdx.x;
  const int rowBase = blockIdx.y * 64;
  const int colBase = blockIdx.x * 64;

  const int lr = tid & 63;   // row within tile for staging
  const int lq = tid >> 6;   // 0..3

  const float* Arow = A + (size_t)(rowBase + lr) * DD;
  const float* Brow = B + (size_t)(colBase + lr) * DD;

  float acc[4][4];
#pragma unroll
  for (int i = 0; i < 4; ++i)
#pragma unroll
    for (int j = 0; j < 4; ++j) acc[i][j] = 0.f;

  const int tx = tid & 15, ty = tid >> 4;

  for (int kb = 0; kb < DD; kb += 32) {
#pragma unroll
    for (int qq = 0; qq < 2; ++qq) {
      const int q = lq + qq * 4;  // 0..7, covers k offsets q*4..q*4+3
      const float4 av = *(const float4*)(Arow + kb + q * 4);
      const float4 bv = *(const float4*)(Brow + kb + q * 4);
      lds_a[(q * 4 + 0) * 64 + lr] = av.x;
      lds_a[(q * 4 + 1) * 64 + lr] = av.y;
      lds_a[(q * 4 + 2) * 64 + lr] = av.z;
      lds_a[(q * 4 + 3) * 64 + lr] = av.w;
      lds_b[(q * 4 + 0) * 64 + lr] = bv.x;
      lds_b[(q * 4 + 1) * 64 + lr] = bv.y;
      lds_b[(q * 4 + 2) * 64 + lr] = bv.z;
      lds_b[(q * 4 + 3) * 64 + lr] = bv.w;
    }
    __syncthreads();
#pragma unroll
    for (int k = 0; k < 32; ++k) {
      const float4 a4 = *(const float4*)(&lds_a[k * 64 + ty * 4]);
      const float4 b4 = *(const float4*)(&lds_b[k * 64 + tx * 4]);
      const float as0[4] = {a4.x, a4.y, a4.z, a4.w};
      const float bs0[4] = {b4.x, b4.y, b4.z, b4.w};
#pragma unroll
      for (int ii = 0; ii < 4; ++ii)
#pragma unroll
        for (int jj = 0; jj < 4; ++jj)
          acc[ii][jj] = fmaf(as0[ii], bs0[jj], acc[ii][jj]);
    }
    __syncthreads();
  }

#pragma unroll
  for (int ii = 0; ii < 4; ++ii) {
    const int gr = rowBase + ty * 4 + ii;
    const float sa = scales[pA * NN + gr];
#pragma unroll
    for (int jj = 0; jj < 4; ++jj) {
      const int gc = colBase + tx * 4 + jj;
      const float sb = scales[pB * NN + gc];
      C[gr * NN + gc] = 1.0f - acc[ii][jj] * sa * sb;
    }
  }
}

// ---------------- exact JV shortest-augmenting-path LAP, one block per problem ----------
// Thread tid owns column tid. float64 duals to match reference solve_lap_np.
__global__ __launch_bounds__(512) void lap_kernel(
    const float* __restrict__ cost_all, float* __restrict__ out) {
  const int p = blockIdx.x;
  const float* cost = cost_all + (size_t)p * NN * NN;
  float* outp = out + (size_t)p * NN * NN;
  const int tid = threadIdx.x;

  __shared__ double sh_u[NN];
  __shared__ double sh_shortest[NN];
  __shared__ int sh_path[NN];
  __shared__ int sh_col4row[NN];
  __shared__ int sh_row4col[NN];
  __shared__ double red_val[8];
  __shared__ int red_idx[8];
  __shared__ int sh_i, sh_sink, sh_bi;
  __shared__ double sh_minval;

  const double INF = __builtin_inf();

  sh_u[tid] = 0.0;
  sh_col4row[tid] = -1;
  sh_row4col[tid] = -1;
  double myV = 0.0;  // v[tid] lives in a register (only owner reads/writes)
  __syncthreads();

  for (int cur_row = 0; cur_row < NN; ++cur_row) {
    double myShortest = INF;
    bool mySC = false, mySR = false;
    if (tid == 0) { sh_i = cur_row; sh_sink = -1; sh_minval = 0.0; }
    __syncthreads();

    int sink = -1;
    while (true) {
      const int i = sh_i;            // current row (uniform)
      const double minv = sh_minval; // shortest[j*] so far (uniform)
      if (tid == i) mySR = true;
      const double u_i = sh_u[i];    // LDS broadcast
      double val;
      if (!mySC) {
        const double r = minv + (double)cost[i * NN + tid] - u_i - myV;
        if (r < myShortest) {
          myShortest = r;
          sh_path[tid] = i;
        }
        val = myShortest;
      } else {
        val = INF;
      }
      int idx = tid;
      // per-wave argmin, tie-break smallest index (matches np.argmin)
#pragma unroll
      for (int off = 32; off > 0; off >>= 1) {
        const double oval = __shfl_down(val, off);
        const int oidx = __shfl_down(idx, off);
        if (oval < val || (oval == val && oidx < idx)) { val = oval; idx = oidx; }
      }
      if ((tid & 63) == 0) { red_val[tid >> 6] = val; red_idx[tid >> 6] = idx; }
      sh_shortest[tid] = myShortest;  // keep LDS copy current for dual updates
      __syncthreads();
      if (tid == 0) {
        double bv = red_val[0];
        int bi = red_idx[0];
#pragma unroll
        for (int w = 1; w < 8; ++w) {  // ascending wave => ascending idx, strict < keeps ties at smaller idx
          if (red_val[w] < bv) { bv = red_val[w]; bi = red_idx[w]; }
        }
        sh_minval = bv;
        sh_bi = bi;
        const int r4c = sh_row4col[bi];
        if (r4c < 0) sh_sink = bi; else sh_i = r4c;
      }
      __syncthreads();
      if (tid == sh_bi) mySC = true;
      sink = sh_sink;
      if (sink >= 0) break;
    }

    const double minv = sh_minval;
    // dual updates (before augmentation, like the reference)
    if (tid == cur_row) {
      sh_u[tid] += minv;
    } else if (mySR) {
      sh_u[tid] += minv - sh_shortest[sh_col4row[tid]];
    }
    if (mySC) {
      myV -= minv - myShortest;
    }
    __syncthreads();
    // augment along alternating path (short chain, serial on thread 0)
    if (tid == 0) {
      int j = sink;
      while (true) {
        const int i = sh_path[j];
        sh_row4col[j] = i;
        const int tmp = sh_col4row[i];
        sh_col4row[i] = j;
        j = tmp;
        if (i == cur_row) break;
      }
    }
    __syncthreads();
  }

  outp[(size_t)tid * NN + sh_col4row[tid]] = 1.0f;
}

extern "C" void kernel_launch(void* const* d_in, const int* in_sizes, int n_in,
                              void* d_out, int out_size, void* d_ws, size_t ws_size,
                              hipStream_t stream) {
  const float* un1 = (const float*)d_in[0];
  const float* un2 = (const float*)d_in[1];
  const float* un3 = (const float*)d_in[2];
  float* out = (float*)d_out;

  float* cost = (float*)d_ws;                       // 3 * 512 * 512 floats
  float* scales = cost + (size_t)3 * NN * NN;       // 3 * 512 floats

  hipMemsetAsync(d_out, 0, (size_t)out_size * sizeof(float), stream);

  norm_kernel<<<dim3(NN, 3), 256, 0, stream>>>(un1, un2, un3, scales);
  cost_gemm_kernel<<<dim3(NN / 64, NN / 64, 3), 256, 0, stream>>>(un1, un2, un3, scales, cost);
  lap_kernel<<<3, NN, 0, stream>>>(cost, out);
}